// Round 6
// baseline (257.587 us; speedup 1.0000x reference)
//
#include <hip/hip_runtime.h>

#define NN 100000
#define NE 1280000
#define D  64

#define BINSZ   512
#define NBIN    196            // ceil(NN/512); 196*512 = 100352
#define ESTRIDE 7168           // max edges/bin (mean 6554, +7.6 sigma); 7*1024
#define CHUNK   4096           // edges per bin_scatter block
#define NT      (NN / 16)      // 6250 MFMA node-tiles

typedef unsigned int   uint;
typedef unsigned short ushort;
typedef unsigned char  uchar;
typedef __attribute__((ext_vector_type(8))) short short8v;   // 8 bf16
typedef __attribute__((ext_vector_type(4))) float f32x4;

// float -> bf16 round-to-nearest-even
__device__ __forceinline__ ushort f2bf(float f) {
    uint u = __float_as_uint(f);
    uint r = (u + 0x7fffu + ((u >> 16) & 1u)) >> 16;
    return (ushort)r;
}
__device__ __forceinline__ float bf2f(ushort h) {
    return __uint_as_float(((uint)h) << 16);
}
__device__ __forceinline__ float bfhi_f(uint w) { return __uint_as_float(w & 0xffff0000u); }
__device__ __forceinline__ float bflo_f(uint w) { return __uint_as_float(w << 16); }
__device__ __forceinline__ uint packbf(float a, float b) {
    return (uint)f2bf(a) | ((uint)f2bf(b) << 16);
}

// ---------------------------------------------------------------------------
// prep (merged): blocks [0,3125) convert x -> packed bf16 (16B/thread);
// blocks [3125,3189) split the 4 weight matrices into hi/lo bf16.
// ---------------------------------------------------------------------------
#define XBLKS 3125             // NN*64 floats / (8 floats/thread) / 256
__global__ __launch_bounds__(256) void prep(const float* __restrict__ x,
                                            uint* __restrict__ xb,
                                            const float* __restrict__ w0,
                                            const float* __restrict__ w1,
                                            const float* __restrict__ w2,
                                            const float* __restrict__ w3,
                                            ushort* __restrict__ hi,
                                            ushort* __restrict__ lo) {
    const int bid = blockIdx.x;
    if (bid < XBLKS) {
        const int g = bid * 256 + threadIdx.x;        // < 800000
        const float4* xp = (const float4*)x + (size_t)g * 2;
        const float4 v0 = xp[0], v1 = xp[1];
        uint4 o;
        o.x = packbf(v0.x, v0.y);
        o.y = packbf(v0.z, v0.w);
        o.z = packbf(v1.x, v1.y);
        o.w = packbf(v1.z, v1.w);
        ((uint4*)xb)[g] = o;
    } else {
        const int g = (bid - XBLKS) * 256 + threadIdx.x;   // < 16384
        if (g < 4 * 4096) {
            const int m = g >> 12;
            const float* src = (m == 0) ? w0 : (m == 1) ? w1 : (m == 2) ? w2 : w3;
            const float f = src[g & 4095];
            const ushort h = f2bf(f);
            hi[g] = h;
            lo[g] = f2bf(f - bf2f(h));
        }
    }
}

// ---------------------------------------------------------------------------
// bin_scatter: group edges by 512-node dst-bin with dense run writes.
// Rank-from-histogram: the counting atomicAdd returns the within-(block,bin)
// rank, so placement needs no second atomic pass.
// Packed edge: (src << 9) | (dst & 511).
// ---------------------------------------------------------------------------
__global__ __launch_bounds__(256) void bin_scatter(const int* __restrict__ srcv,
                                                   const int* __restrict__ dstv,
                                                   int* __restrict__ bincur,
                                                   uint* __restrict__ ecol) {
    __shared__ uint  ebuf[CHUNK];     // 16 KB
    __shared__ uchar bbuf[CHUNK];     // 4 KB
    __shared__ int hist[256];
    __shared__ int hbase[256];
    __shared__ int gbase[256];

    const int tid  = threadIdx.x;
    const int base = blockIdx.x * CHUNK;

    hist[tid] = 0;
    __syncthreads();

    uint pk[16];
    int  bn[16], rk[16];
    #pragma unroll
    for (int r = 0; r < 16; ++r) {
        const int e = base + r * 256 + tid;
        if (e < NE) {
            const int d = dstv[e];
            bn[r] = d >> 9;
            pk[r] = ((uint)srcv[e] << 9) | (uint)(d & 511);
            rk[r] = atomicAdd(&hist[bn[r]], 1);
        } else {
            bn[r] = -1;
        }
    }
    __syncthreads();

    // exclusive scan of per-bin counts
    const int v = hist[tid];
    hbase[tid] = v;
    __syncthreads();
    for (int d = 1; d < 256; d <<= 1) {
        const int t = (tid >= d) ? hbase[tid - d] : 0;
        __syncthreads();
        hbase[tid] += t;
        __syncthreads();
    }
    hbase[tid] -= v;                       // own-index, safe
    // claim contiguous global space per nonempty bin
    if (tid < NBIN && v > 0)
        gbase[tid] = atomicAdd(&bincur[tid], v);
    __syncthreads();

    // placement (no atomics)
    #pragma unroll
    for (int r = 0; r < 16; ++r) {
        if (bn[r] >= 0) {
            const int p = hbase[bn[r]] + rk[r];
            ebuf[p] = pk[r];
            bbuf[p] = (uchar)bn[r];
        }
    }
    __syncthreads();

    // coalesced run copy-out
    const int n = min(CHUNK, NE - base);
    for (int i = tid; i < n; i += 256) {
        const int b   = bbuf[i];
        const int pib = gbase[b] + (i - hbase[b]);
        if (pib < ESTRIDE)
            ecol[(size_t)b * ESTRIDE + pib] = ebuf[i];
    }
}

// ---------------------------------------------------------------------------
// binsort: one block per bin. Recomputes the 196-entry bin-base prefix in
// one wave (binscan kernel eliminated). Counting-sort by node with
// rank-from-histogram; col placement writes go DIRECT to global (28 KB bin
// region, single block/XCD -> L2 absorbs). Emits CSR offs.
// ---------------------------------------------------------------------------
__global__ __launch_bounds__(1024) void binsort(const uint* __restrict__ ecol,
                                                const int* __restrict__ bincur,
                                                int* __restrict__ col,
                                                int* __restrict__ offs) {
    __shared__ int hist[512];
    __shared__ int cnt_[512];
    __shared__ int gdst_s;

    const int b = blockIdx.x;
    const int t = threadIdx.x;
    const int n    = min(bincur[b], ESTRIDE);
    const int gsrc = b * ESTRIDE;

    if (t < 512) hist[t] = 0;
    if (t < 64) {                      // wave 0: prefix of bins < b
        int s = 0;
        for (int i = t; i < b; i += 64) s += min(bincur[i], ESTRIDE);
        #pragma unroll
        for (int d = 1; d < 64; d <<= 1) s += __shfl_xor(s, d);
        if (t == 0) gdst_s = s;
    }
    __syncthreads();
    const int gdst = gdst_s;

    const int NIT = ESTRIDE / 1024;    // 7
    int nd[NIT], ee[NIT], rk[NIT];
    #pragma unroll
    for (int it = 0; it < NIT; ++it) {
        const int i = t + it * 1024;
        if (i < n) {
            const uint e = ecol[gsrc + i];
            nd[it] = (int)(e & 511);
            ee[it] = (int)(e >> 9);
            rk[it] = atomicAdd(&hist[nd[it]], 1);
        } else {
            nd[it] = -1;
        }
    }
    __syncthreads();

    // exclusive scan of hist (512) -> hist holds exclusive offsets
    int v = 0;
    if (t < 512) { v = hist[t]; cnt_[t] = v; }
    __syncthreads();
    for (int d = 1; d < 512; d <<= 1) {
        const int tv = (t >= d && t < 512) ? hist[t - d] : 0;
        __syncthreads();
        if (t < 512) hist[t] += tv;
        __syncthreads();
    }
    if (t < 512) {
        const int excl = hist[t] - cnt_[t];
        hist[t] = excl;
        const int node = b * BINSZ + t;
        if (node < NN) offs[node] = gdst + excl;
        if (b == NBIN - 1 && node == NN - 1) offs[NN] = gdst + n;
    }
    __syncthreads();

    #pragma unroll
    for (int it = 0; it < NIT; ++it)
        if (nd[it] >= 0)
            col[gdst + hist[nd[it]] + rk[it]] = ee[it];
}

// ---------------------------------------------------------------------------
// fused_layer: wave per 16-node tile, lane l = (node l&15, feature-quarter
// l>>4), aggregation straight into MFMA A-frag layout. A/B double-buffered
// gather pipeline (16 loads in flight); non-temporal col reads and output
// stores keep the hot gather table resident in L2.
// ---------------------------------------------------------------------------
__device__ __forceinline__ void gload(int (&id)[4], uint4 (&r0)[4], uint4 (&r1)[4],
                                      int k0, int deg, const int* __restrict__ col,
                                      int o0, const uint* __restrict__ gsrc, int q) {
    #pragma unroll
    for (int u = 0; u < 4; ++u) {
        const int k = k0 + u;
        id[u] = (k < deg) ? __builtin_nontemporal_load(col + o0 + k) : -1;
    }
    #pragma unroll
    for (int u = 0; u < 4; ++u) {
        if (id[u] >= 0) {
            const uint* row = gsrc + (size_t)id[u] * 32;
            r0[u] = *(const uint4*)(row + 4 * q);
            r1[u] = *(const uint4*)(row + 16 + 4 * q);
        }
    }
}

__device__ __forceinline__ void gconsume(const int (&id)[4], const uint4 (&r0)[4],
                                         const uint4 (&r1)[4], float (&acc)[16]) {
    #pragma unroll
    for (int u = 0; u < 4; ++u) {
        if (id[u] >= 0) {
            uint w;
            w = r0[u].x; acc[0]  += bflo_f(w); acc[1]  += bfhi_f(w);
            w = r0[u].y; acc[2]  += bflo_f(w); acc[3]  += bfhi_f(w);
            w = r0[u].z; acc[4]  += bflo_f(w); acc[5]  += bfhi_f(w);
            w = r0[u].w; acc[6]  += bflo_f(w); acc[7]  += bfhi_f(w);
            w = r1[u].x; acc[8]  += bflo_f(w); acc[9]  += bfhi_f(w);
            w = r1[u].y; acc[10] += bflo_f(w); acc[11] += bfhi_f(w);
            w = r1[u].z; acc[12] += bflo_f(w); acc[13] += bfhi_f(w);
            w = r1[u].w; acc[14] += bflo_f(w); acc[15] += bfhi_f(w);
        }
    }
}

template<int SELF_BF16, int WF32, int WB16>
__global__ __launch_bounds__(256) void fused_layer(
        const uint*   __restrict__ gsrc,   // packed bf16 gather source [NN][32]
        const float*  __restrict__ selff,  // fp32 self rows (layer 1)
        const ushort* __restrict__ selfb,  // bf16 self rows (layer 2)
        const int*    __restrict__ col,
        const int*    __restrict__ offs,
        const ushort* __restrict__ wl_hi, const ushort* __restrict__ wl_lo,
        const ushort* __restrict__ wr_hi, const ushort* __restrict__ wr_lo,
        const float*  __restrict__ bias,
        float* __restrict__ outf, ushort* __restrict__ outb,
        int do_relu)
{
    const int l   = threadIdx.x & 63;
    const int wid = (blockIdx.x * 256 + threadIdx.x) >> 6;
    if (wid >= NT) return;
    const int m16   = l & 15;
    const int q     = l >> 4;        // 0..3
    const int koff  = q * 8;
    const int mbase = wid * 16;
    const int node  = mbase + m16;

    const int o0  = offs[node];
    const int deg = offs[node + 1] - o0;

    float acc[16];
    #pragma unroll
    for (int j = 0; j < 16; ++j) acc[j] = 0.f;

    int idA[4], idB[4];
    uint4 a0[4], a1[4], b0[4], b1[4];

    if (__any(deg > 0)) {
        gload(idA, a0, a1, 0, deg, col, o0, gsrc, q);
        int k = 4;
        for (;;) {
            const bool more = __any(k < deg);
            if (more) gload(idB, b0, b1, k, deg, col, o0, gsrc, q);
            gconsume(idA, a0, a1, acc);
            if (!more) break;
            k += 4;
            const bool more2 = __any(k < deg);
            if (more2) gload(idA, a0, a1, k, deg, col, o0, gsrc, q);
            gconsume(idB, b0, b1, acc);
            if (!more2) break;
            k += 4;
        }
    }

    const float inv = 1.0f / (float)max(deg, 1);
    short8v am[2];
    #pragma unroll
    for (int j = 0; j < 8; ++j) {
        am[0][j] = (short)f2bf(acc[j] * inv);
        am[1][j] = (short)f2bf(acc[8 + j] * inv);
    }

    // ---- self fragments ----
    short8v ashi[2], aslo[2];
    if (SELF_BF16) {
        ashi[0] = *(const short8v*)(selfb + (size_t)node * 64 + koff);
        ashi[1] = *(const short8v*)(selfb + (size_t)node * 64 + 32 + koff);
    } else {
        #pragma unroll
        for (int kk = 0; kk < 2; ++kk) {
            const float4* xp = (const float4*)(selff + (size_t)node * 64 + kk * 32 + koff);
            const float4 v0 = xp[0], v1 = xp[1];
            const float vv[8] = {v0.x, v0.y, v0.z, v0.w, v1.x, v1.y, v1.z, v1.w};
            #pragma unroll
            for (int j = 0; j < 8; ++j) {
                const ushort hb_ = f2bf(vv[j]);
                ashi[kk][j] = (short)hb_;
                aslo[kk][j] = (short)f2bf(vv[j] - bf2f(hb_));
            }
        }
    }

    // ---- MFMA combine (round-3-verified mapping) ----
    #pragma unroll
    for (int nt = 0; nt < 4; ++nt) {
        f32x4 acc4 = {0.f, 0.f, 0.f, 0.f};
        #pragma unroll
        for (int kk = 0; kk < 2; ++kk) {
            const size_t wo = (size_t)(nt * 16 + m16) * 64 + kk * 32 + koff;
            const short8v bwlh = *(const short8v*)(wl_hi + wo);
            const short8v bwll = *(const short8v*)(wl_lo + wo);
            const short8v bwrh = *(const short8v*)(wr_hi + wo);
            const short8v bwrl = *(const short8v*)(wr_lo + wo);
            acc4 = __builtin_amdgcn_mfma_f32_16x16x32_bf16(am[kk],   bwlh, acc4, 0, 0, 0);
            acc4 = __builtin_amdgcn_mfma_f32_16x16x32_bf16(am[kk],   bwll, acc4, 0, 0, 0);
            acc4 = __builtin_amdgcn_mfma_f32_16x16x32_bf16(ashi[kk], bwrh, acc4, 0, 0, 0);
            if (!SELF_BF16)
                acc4 = __builtin_amdgcn_mfma_f32_16x16x32_bf16(aslo[kk], bwrh, acc4, 0, 0, 0);
            acc4 = __builtin_amdgcn_mfma_f32_16x16x32_bf16(ashi[kk], bwrl, acc4, 0, 0, 0);
        }
        const float bv = bias[nt * 16 + m16];
        #pragma unroll
        for (int r = 0; r < 4; ++r) {
            float v = acc4[r] + bv;
            if (do_relu) v = fmaxf(v, 0.f);
            const size_t oi = (size_t)(mbase + q * 4 + r) * 64 + nt * 16 + m16;
            if (WF32) __builtin_nontemporal_store(v, &outf[oi]);
            if (WB16) __builtin_nontemporal_store(f2bf(v), &outb[oi]);
        }
    }
}

// ---------------------------------------------------------------------------
extern "C" void kernel_launch(void* const* d_in, const int* in_sizes, int n_in,
                              void* d_out, int out_size, void* d_ws, size_t ws_size,
                              hipStream_t stream) {
    const float* x   = (const float*)d_in[0];
    const int*   ei  = (const int*)d_in[1];     // [2, NE] int32
    const float* W1l = (const float*)d_in[2];
    const float* b1  = (const float*)d_in[3];
    const float* W1r = (const float*)d_in[4];
    const float* W2l = (const float*)d_in[5];
    const float* b2  = (const float*)d_in[6];
    const float* W2r = (const float*)d_in[7];
    float*       out = (float*)d_out;

    const int* src = ei;
    const int* dst = ei + NE;

    // ---- workspace layout (~31.2 MB; ecol aliased inside hb) ----
    char* p = (char*)d_ws;
    int*    bincur = (int*)p;    p += 1024;
    int*    col    = (int*)p;    p += (size_t)NE * 4;              // 5.12 MB
    int*    offs   = (int*)p;    p += (size_t)(NN + 1) * 4 + 60;   // 0.4 MB
    ushort* whi    = (ushort*)p; p += (size_t)4 * 4096 * 2;        // 32 KB
    ushort* wlo    = (ushort*)p; p += (size_t)4 * 4096 * 2;        // 32 KB
    uint*   xb     = (uint*)p;   p += (size_t)NN * 32 * 4;         // 12.8 MB
    uint*   hb     = (uint*)p;   p += (size_t)NN * 32 * 4;         // 12.8 MB
    uint*   ecol   = hb;   // 5.62 MB, dead before hb is written (stream-serial)

    const ushort* w1l_hi = whi;             const ushort* w1l_lo = wlo;
    const ushort* w1r_hi = whi + 4096;      const ushort* w1r_lo = wlo + 4096;
    const ushort* w2l_hi = whi + 2 * 4096;  const ushort* w2l_lo = wlo + 2 * 4096;
    const ushort* w2r_hi = whi + 3 * 4096;  const ushort* w2r_lo = wlo + 3 * 4096;

    hipMemsetAsync(bincur, 0, 1024, stream);

    // ---- prep (x -> bf16, W -> hi/lo) ----
    prep<<<XBLKS + 64, 256, 0, stream>>>(x, xb, W1l, W1r, W2l, W2r, whi, wlo);

    // ---- CSR build ----
    bin_scatter<<<(NE + CHUNK - 1) / CHUNK, 256, 0, stream>>>(src, dst, bincur, ecol);
    binsort<<<NBIN, 1024, 0, stream>>>(ecol, bincur, col, offs);

    // ---- layer 1: gather xb, self x (fp32), write h (bf16) ----
    fused_layer<0, 0, 1><<<(NT * 64 + 255) / 256, 256, 0, stream>>>(
        xb, x, nullptr, col, offs,
        w1l_hi, w1l_lo, w1r_hi, w1r_lo, b1, nullptr, (ushort*)hb, 1);

    // ---- layer 2: gather hb, self hb (bf16), write out (fp32) ----
    fused_layer<1, 1, 0><<<(NT * 64 + 255) / 256, 256, 0, stream>>>(
        hb, nullptr, (const ushort*)hb, col, offs,
        w2l_hi, w2l_lo, w2r_hi, w2r_lo, b2, out, nullptr, 0);
}

// Round 7
// 244.358 us; speedup vs baseline: 1.0541x; 1.0541x over previous
//
#include <hip/hip_runtime.h>

#define NN 100000
#define NE 1280000
#define D  64

#define BINSZ   512
#define NBIN    196            // ceil(NN/512); 196*512 = 100352
#define ESTRIDE 7168           // max edges/bin (mean 6554, +7.6 sigma); 7*1024
#define CHUNK   4096           // edges per scatter chunk
#define NT      (NN / 16)      // 6250 MFMA node-tiles
#define NSHARD  16             // src>>13 -> 0..12 used
#define NBUCKET (BINSZ * NSHARD)   // 8192 counters in binsort

#define SCATB   ((NE + CHUNK - 1) / CHUNK)   // 313 scatter blocks
#define XBLKS   3125           // NN*64 floats / 8 per thread / 256
#define WBLKS   64             // 4*4096 weight elems / 256

typedef unsigned int   uint;
typedef unsigned short ushort;
typedef unsigned char  uchar;
typedef __attribute__((ext_vector_type(8))) short short8v;   // 8 bf16
typedef __attribute__((ext_vector_type(4))) float f32x4;

// float -> bf16 round-to-nearest-even
__device__ __forceinline__ ushort f2bf(float f) {
    uint u = __float_as_uint(f);
    uint r = (u + 0x7fffu + ((u >> 16) & 1u)) >> 16;
    return (ushort)r;
}
__device__ __forceinline__ float bf2f(ushort h) {
    return __uint_as_float(((uint)h) << 16);
}
__device__ __forceinline__ float bfhi_f(uint w) { return __uint_as_float(w & 0xffff0000u); }
__device__ __forceinline__ float bflo_f(uint w) { return __uint_as_float(w << 16); }
__device__ __forceinline__ uint packbf(float a, float b) {
    return (uint)f2bf(a) | ((uint)f2bf(b) << 16);
}

// ---------------------------------------------------------------------------
// scatter_prep (merged): blocks [0,SCATB) group edges by 512-node dst-bin
// (dense run writes, rank-from-histogram); blocks [SCATB, SCATB+XBLKS)
// convert x -> packed bf16; remaining blocks split weights into hi/lo bf16.
// Packed edge: (src << 9) | (dst & 511).
// ---------------------------------------------------------------------------
__global__ __launch_bounds__(256) void scatter_prep(
        const int* __restrict__ srcv, const int* __restrict__ dstv,
        int* __restrict__ bincur, uint* __restrict__ ecol,
        const float* __restrict__ x, uint* __restrict__ xb,
        const float* __restrict__ w0, const float* __restrict__ w1,
        const float* __restrict__ w2, const float* __restrict__ w3,
        ushort* __restrict__ hi, ushort* __restrict__ lo) {
    __shared__ uint  ebuf[CHUNK];     // 16 KB
    __shared__ uchar bbuf[CHUNK];     // 4 KB
    __shared__ int hist[256];
    __shared__ int hbase[256];
    __shared__ int gbase[256];

    const int bid = blockIdx.x;
    const int tid = threadIdx.x;

    if (bid >= SCATB) {                       // ---- prep path ----
        if (bid < SCATB + XBLKS) {
            const int g = (bid - SCATB) * 256 + tid;          // < 800000
            const float4* xp = (const float4*)x + (size_t)g * 2;
            const float4 v0 = xp[0], v1 = xp[1];
            uint4 o;
            o.x = packbf(v0.x, v0.y);
            o.y = packbf(v0.z, v0.w);
            o.z = packbf(v1.x, v1.y);
            o.w = packbf(v1.z, v1.w);
            ((uint4*)xb)[g] = o;
        } else {
            const int g = (bid - SCATB - XBLKS) * 256 + tid;  // < 16384
            if (g < 4 * 4096) {
                const int m = g >> 12;
                const float* src = (m == 0) ? w0 : (m == 1) ? w1 : (m == 2) ? w2 : w3;
                const float f = src[g & 4095];
                const ushort h = f2bf(f);
                hi[g] = h;
                lo[g] = f2bf(f - bf2f(h));
            }
        }
        return;
    }

    // ---- scatter path ----
    const int base = bid * CHUNK;

    hist[tid] = 0;
    __syncthreads();

    uint pk[16];
    int  bn[16], rk[16];
    #pragma unroll
    for (int r = 0; r < 16; ++r) {
        const int e = base + r * 256 + tid;
        if (e < NE) {
            const int d = dstv[e];
            bn[r] = d >> 9;
            pk[r] = ((uint)srcv[e] << 9) | (uint)(d & 511);
            rk[r] = atomicAdd(&hist[bn[r]], 1);
        } else {
            bn[r] = -1;
        }
    }
    __syncthreads();

    // exclusive scan of per-bin counts
    const int v = hist[tid];
    hbase[tid] = v;
    __syncthreads();
    for (int d = 1; d < 256; d <<= 1) {
        const int t = (tid >= d) ? hbase[tid - d] : 0;
        __syncthreads();
        hbase[tid] += t;
        __syncthreads();
    }
    hbase[tid] -= v;
    if (tid < NBIN && v > 0)
        gbase[tid] = atomicAdd(&bincur[tid], v);
    __syncthreads();

    // placement (rank-from-histogram, no second atomic pass)
    #pragma unroll
    for (int r = 0; r < 16; ++r) {
        if (bn[r] >= 0) {
            const int p = hbase[bn[r]] + rk[r];
            ebuf[p] = pk[r];
            bbuf[p] = (uchar)bn[r];
        }
    }
    __syncthreads();

    // coalesced run copy-out
    const int n = min(CHUNK, NE - base);
    for (int i = tid; i < n; i += 256) {
        const int b   = bbuf[i];
        const int pib = gbase[b] + (i - hbase[b]);
        if (pib < ESTRIDE)
            ecol[(size_t)b * ESTRIDE + pib] = ebuf[i];
    }
}

// ---------------------------------------------------------------------------
// binsort: one block per bin. Counting-sort by (dst_local, src>>13) with
// 8192 buckets -> each node's neighbor list is src-shard-ordered (L2
// locality window for the gather). Rank-from-histogram; direct global col
// writes; emits CSR offs. 3-barrier wave-based scan of the 8192 counters.
// ---------------------------------------------------------------------------
__global__ __launch_bounds__(1024) void binsort(const uint* __restrict__ ecol,
                                                const int* __restrict__ bincur,
                                                int* __restrict__ col,
                                                int* __restrict__ offs) {
    __shared__ int hist[NBUCKET];   // 32 KB
    __shared__ int wpart[16];
    __shared__ int gdst_s;

    const int b = blockIdx.x;
    const int t = threadIdx.x;
    const int lane = t & 63;
    const int wv   = t >> 6;        // 0..15
    const int n    = min(bincur[b], ESTRIDE);
    const int gsrc = b * ESTRIDE;

    #pragma unroll
    for (int j = 0; j < NBUCKET / 1024; ++j) hist[t + j * 1024] = 0;

    if (wv == 0) {                  // wave 0: prefix of bins < b
        int s = 0;
        for (int i = lane; i < b; i += 64) s += min(bincur[i], ESTRIDE);
        #pragma unroll
        for (int d = 1; d < 64; d <<= 1) s += __shfl_xor(s, d);
        if (lane == 0) gdst_s = s;
    }
    __syncthreads();
    const int gdst = gdst_s;

    // count + rank.  bucket = (dst_local << 4) | (src >> 13) = ((e&511)<<4)|(e>>22)
    const int NIT = ESTRIDE / 1024;    // 7
    int bk[NIT], sv[NIT], rk[NIT];
    #pragma unroll
    for (int it = 0; it < NIT; ++it) {
        const int i = t + it * 1024;
        if (i < n) {
            const uint e = ecol[gsrc + i];
            bk[it] = (int)(((e & 511u) << 4) | (e >> 22));
            sv[it] = (int)(e >> 9);
            rk[it] = atomicAdd(&hist[bk[it]], 1);
        } else {
            bk[it] = -1;
        }
    }
    __syncthreads();

    // exclusive scan of the 8192 counters: thread t owns hist[8t..8t+8)
    int own[8], s = 0;
    #pragma unroll
    for (int j = 0; j < 8; ++j) { own[j] = hist[t * 8 + j]; s += own[j]; }
    int incl = s;
    #pragma unroll
    for (int d = 1; d < 64; d <<= 1) {
        const int up = __shfl_up(incl, d);
        if (lane >= d) incl += up;
    }
    if (lane == 63) wpart[wv] = incl;
    __syncthreads();
    if (wv == 0) {
        int p = (lane < 16) ? wpart[lane] : 0;
        int ip = p;
        #pragma unroll
        for (int d = 1; d < 16; d <<= 1) {
            const int up = __shfl_up(ip, d);
            if (lane >= d) ip += up;
        }
        if (lane < 16) wpart[lane] = ip - p;   // exclusive wave base
    }
    __syncthreads();
    int run = wpart[wv] + incl - s;            // thread-exclusive base
    #pragma unroll
    for (int j = 0; j < 8; ++j) { const int c = own[j]; hist[t * 8 + j] = run; run += c; }
    __syncthreads();

    // CSR offsets (bucket node*16 is the node's first bucket)
    if (t < BINSZ) {
        const int node = b * BINSZ + t;
        if (node < NN) offs[node] = gdst + hist[t * 16];
        if (b == NBIN - 1 && node == NN - 1) offs[NN] = gdst + n;
    }

    // placement: direct global writes (28 KB bin region, L2-absorbed)
    #pragma unroll
    for (int it = 0; it < NIT; ++it)
        if (bk[it] >= 0)
            col[gdst + hist[bk[it]] + rk[it]] = sv[it];
}

// ---------------------------------------------------------------------------
// fused_layer (round-5 body, nontemporal reverted): wave per 16-node tile,
// lane l = (node l&15, feature-quarter l>>4); aggregation straight into MFMA
// A-frag layout; A/B software pipeline; MFMA combine + bias/relu epilogue.
// ---------------------------------------------------------------------------
__device__ __forceinline__ void gload(int (&id)[4], uint4 (&r0)[4], uint4 (&r1)[4],
                                      int k0, int deg, const int* __restrict__ col,
                                      int o0, const uint* __restrict__ gsrc, int q) {
    #pragma unroll
    for (int u = 0; u < 4; ++u) {
        const int k = k0 + u;
        id[u] = (k < deg) ? col[o0 + k] : -1;
    }
    #pragma unroll
    for (int u = 0; u < 4; ++u) {
        if (id[u] >= 0) {
            const uint* row = gsrc + (size_t)id[u] * 32;
            r0[u] = *(const uint4*)(row + 4 * q);
            r1[u] = *(const uint4*)(row + 16 + 4 * q);
        }
    }
}

__device__ __forceinline__ void gconsume(const int (&id)[4], const uint4 (&r0)[4],
                                         const uint4 (&r1)[4], float (&acc)[16]) {
    #pragma unroll
    for (int u = 0; u < 4; ++u) {
        if (id[u] >= 0) {
            uint w;
            w = r0[u].x; acc[0]  += bflo_f(w); acc[1]  += bfhi_f(w);
            w = r0[u].y; acc[2]  += bflo_f(w); acc[3]  += bfhi_f(w);
            w = r0[u].z; acc[4]  += bflo_f(w); acc[5]  += bfhi_f(w);
            w = r0[u].w; acc[6]  += bflo_f(w); acc[7]  += bfhi_f(w);
            w = r1[u].x; acc[8]  += bflo_f(w); acc[9]  += bfhi_f(w);
            w = r1[u].y; acc[10] += bflo_f(w); acc[11] += bfhi_f(w);
            w = r1[u].z; acc[12] += bflo_f(w); acc[13] += bfhi_f(w);
            w = r1[u].w; acc[14] += bflo_f(w); acc[15] += bfhi_f(w);
        }
    }
}

template<int SELF_BF16, int WF32, int WB16>
__global__ __launch_bounds__(256) void fused_layer(
        const uint*   __restrict__ gsrc,   // packed bf16 gather source [NN][32]
        const float*  __restrict__ selff,  // fp32 self rows (layer 1)
        const ushort* __restrict__ selfb,  // bf16 self rows (layer 2)
        const int*    __restrict__ col,
        const int*    __restrict__ offs,
        const ushort* __restrict__ wl_hi, const ushort* __restrict__ wl_lo,
        const ushort* __restrict__ wr_hi, const ushort* __restrict__ wr_lo,
        const float*  __restrict__ bias,
        float* __restrict__ outf, ushort* __restrict__ outb,
        int do_relu)
{
    const int l   = threadIdx.x & 63;
    const int wid = (blockIdx.x * 256 + threadIdx.x) >> 6;
    if (wid >= NT) return;
    const int m16   = l & 15;
    const int q     = l >> 4;        // 0..3
    const int koff  = q * 8;
    const int mbase = wid * 16;
    const int node  = mbase + m16;

    const int o0  = offs[node];
    const int deg = offs[node + 1] - o0;

    float acc[16];
    #pragma unroll
    for (int j = 0; j < 16; ++j) acc[j] = 0.f;

    int idA[4], idB[4];
    uint4 a0[4], a1[4], b0[4], b1[4];

    if (__any(deg > 0)) {
        gload(idA, a0, a1, 0, deg, col, o0, gsrc, q);
        int k = 4;
        for (;;) {
            const bool more = __any(k < deg);
            if (more) gload(idB, b0, b1, k, deg, col, o0, gsrc, q);
            gconsume(idA, a0, a1, acc);
            if (!more) break;
            k += 4;
            const bool more2 = __any(k < deg);
            if (more2) gload(idA, a0, a1, k, deg, col, o0, gsrc, q);
            gconsume(idB, b0, b1, acc);
            if (!more2) break;
            k += 4;
        }
    }

    const float inv = 1.0f / (float)max(deg, 1);
    short8v am[2];
    #pragma unroll
    for (int j = 0; j < 8; ++j) {
        am[0][j] = (short)f2bf(acc[j] * inv);
        am[1][j] = (short)f2bf(acc[8 + j] * inv);
    }

    // ---- self fragments ----
    short8v ashi[2], aslo[2];
    if (SELF_BF16) {
        ashi[0] = *(const short8v*)(selfb + (size_t)node * 64 + koff);
        ashi[1] = *(const short8v*)(selfb + (size_t)node * 64 + 32 + koff);
    } else {
        #pragma unroll
        for (int kk = 0; kk < 2; ++kk) {
            const float4* xp = (const float4*)(selff + (size_t)node * 64 + kk * 32 + koff);
            const float4 v0 = xp[0], v1 = xp[1];
            const float vv[8] = {v0.x, v0.y, v0.z, v0.w, v1.x, v1.y, v1.z, v1.w};
            #pragma unroll
            for (int j = 0; j < 8; ++j) {
                const ushort hb_ = f2bf(vv[j]);
                ashi[kk][j] = (short)hb_;
                aslo[kk][j] = (short)f2bf(vv[j] - bf2f(hb_));
            }
        }
    }

    // ---- MFMA combine ----
    #pragma unroll
    for (int nt = 0; nt < 4; ++nt) {
        f32x4 acc4 = {0.f, 0.f, 0.f, 0.f};
        #pragma unroll
        for (int kk = 0; kk < 2; ++kk) {
            const size_t wo = (size_t)(nt * 16 + m16) * 64 + kk * 32 + koff;
            const short8v bwlh = *(const short8v*)(wl_hi + wo);
            const short8v bwll = *(const short8v*)(wl_lo + wo);
            const short8v bwrh = *(const short8v*)(wr_hi + wo);
            const short8v bwrl = *(const short8v*)(wr_lo + wo);
            acc4 = __builtin_amdgcn_mfma_f32_16x16x32_bf16(am[kk],   bwlh, acc4, 0, 0, 0);
            acc4 = __builtin_amdgcn_mfma_f32_16x16x32_bf16(am[kk],   bwll, acc4, 0, 0, 0);
            acc4 = __builtin_amdgcn_mfma_f32_16x16x32_bf16(ashi[kk], bwrh, acc4, 0, 0, 0);
            if (!SELF_BF16)
                acc4 = __builtin_amdgcn_mfma_f32_16x16x32_bf16(aslo[kk], bwrh, acc4, 0, 0, 0);
            acc4 = __builtin_amdgcn_mfma_f32_16x16x32_bf16(ashi[kk], bwrl, acc4, 0, 0, 0);
        }
        const float bv = bias[nt * 16 + m16];
        #pragma unroll
        for (int r = 0; r < 4; ++r) {
            float v = acc4[r] + bv;
            if (do_relu) v = fmaxf(v, 0.f);
            const size_t oi = (size_t)(mbase + q * 4 + r) * 64 + nt * 16 + m16;
            if (WF32) outf[oi] = v;
            if (WB16) outb[oi] = f2bf(v);
        }
    }
}

// ---------------------------------------------------------------------------
extern "C" void kernel_launch(void* const* d_in, const int* in_sizes, int n_in,
                              void* d_out, int out_size, void* d_ws, size_t ws_size,
                              hipStream_t stream) {
    const float* x   = (const float*)d_in[0];
    const int*   ei  = (const int*)d_in[1];     // [2, NE] int32
    const float* W1l = (const float*)d_in[2];
    const float* b1  = (const float*)d_in[3];
    const float* W1r = (const float*)d_in[4];
    const float* W2l = (const float*)d_in[5];
    const float* b2  = (const float*)d_in[6];
    const float* W2r = (const float*)d_in[7];
    float*       out = (float*)d_out;

    const int* src = ei;
    const int* dst = ei + NE;

    // ---- workspace layout (~31.2 MB; ecol aliased inside hb) ----
    char* p = (char*)d_ws;
    int*    bincur = (int*)p;    p += 1024;
    int*    col    = (int*)p;    p += (size_t)NE * 4;              // 5.12 MB
    int*    offs   = (int*)p;    p += (size_t)(NN + 1) * 4 + 60;   // 0.4 MB
    ushort* whi    = (ushort*)p; p += (size_t)4 * 4096 * 2;        // 32 KB
    ushort* wlo    = (ushort*)p; p += (size_t)4 * 4096 * 2;        // 32 KB
    uint*   xb     = (uint*)p;   p += (size_t)NN * 32 * 4;         // 12.8 MB
    uint*   hb     = (uint*)p;   p += (size_t)NN * 32 * 4;         // 12.8 MB
    uint*   ecol   = hb;   // 5.62 MB, dead before hb is written (stream-serial)

    const ushort* w1l_hi = whi;             const ushort* w1l_lo = wlo;
    const ushort* w1r_hi = whi + 4096;      const ushort* w1r_lo = wlo + 4096;
    const ushort* w2l_hi = whi + 2 * 4096;  const ushort* w2l_lo = wlo + 2 * 4096;
    const ushort* w2r_hi = whi + 3 * 4096;  const ushort* w2r_lo = wlo + 3 * 4096;

    hipMemsetAsync(bincur, 0, 1024, stream);

    // ---- scatter + prep (merged single dispatch) ----
    scatter_prep<<<SCATB + XBLKS + WBLKS, 256, 0, stream>>>(
        src, dst, bincur, ecol, x, xb, W1l, W1r, W2l, W2r, whi, wlo);

    // ---- shard-ordered counting sort -> CSR ----
    binsort<<<NBIN, 1024, 0, stream>>>(ecol, bincur, col, offs);

    // ---- layer 1: gather xb, self x (fp32), write h (bf16) ----
    fused_layer<0, 0, 1><<<(NT * 64 + 255) / 256, 256, 0, stream>>>(
        xb, x, nullptr, col, offs,
        w1l_hi, w1l_lo, w1r_hi, w1r_lo, b1, nullptr, (ushort*)hb, 1);

    // ---- layer 2: gather hb, self hb (bf16), write out (fp32) ----
    fused_layer<1, 1, 0><<<(NT * 64 + 255) / 256, 256, 0, stream>>>(
        hb, nullptr, (const ushort*)hb, col, offs,
        w2l_hi, w2l_lo, w2r_hi, w2r_lo, b2, out, nullptr, 0);
}